// Round 16
// baseline (114.278 us; speedup 1.0000x reference)
//
#include <hip/hip_runtime.h>

#define N_NODES 100000
#define D_FEAT 128
#define CLASSES 64
#define N_EDGES 800000
#define DUMMY N_NODES        // zero row in Y table
#define NPP 64               // nodes per partition
#define NPART 1563           // ceil(N_NODES / NPP)
#define PCAP 768             // per-partition cap: mean 512, +11 sigma
#define CBKT 64              // coarse buckets (dst>>11), 49 used
#define CCAP 18432           // per-bucket cap: mean 16.3k, +16 sigma
#define NSTRIP (N_NODES / 16)  // 6250
#define GEMM_BLOCKS 782
#define BINA_BLOCKS 782
#define TILE_A 1024
#define NTILE_A 782          // ceil(N_EDGES / TILE_A)

typedef short bf16x8 __attribute__((ext_vector_type(8)));
typedef float f32x4 __attribute__((ext_vector_type(4)));
typedef float fvec4 __attribute__((ext_vector_type(4)));

static __device__ __forceinline__ unsigned short f32_to_bf16(float f) {
    unsigned int u = __float_as_uint(f);
    u += 0x7FFFu + ((u >> 16) & 1u);  // round-to-nearest-even
    return (unsigned short)(u >> 16);
}
static __device__ __forceinline__ float bf16_lo(unsigned int u) {
    return __uint_as_float(u << 16);
}
static __device__ __forceinline__ float bf16_hi(unsigned int u) {
    return __uint_as_float(u & 0xFFFF0000u);
}

// Kernel 1: zero coarse tails + dummy Y row.
__global__ void zq_kernel(int* __restrict__ ctail, unsigned int* __restrict__ yb) {
    int i = blockIdx.x * blockDim.x + threadIdx.x;
    if (i < 1024) ctail[i] = 0;
    if (i < 32) yb[(size_t)DUMMY * 32 + i] = 0;
}

// Kernel 2 (fused): blocks [0,GEMM_BLOCKS) = MFMA GEMM Y=X@W (2 strips/wave,
// batched nontemporal loads). Blocks [GEMM_BLOCKS,+BINA_BLOCKS) = coarse
// multisplit (1024-edge tiles, 4 edges/thread, per-wave private histograms,
// 3 barriers/tile). Proven structure from R15.
__global__ __launch_bounds__(256) void fused_gemm_binA_kernel(
        const float* __restrict__ x, const float* __restrict__ W,
        const int* __restrict__ src, const int* __restrict__ dst,
        int* __restrict__ ctail, unsigned int* __restrict__ cbuf,
        unsigned short* __restrict__ ybu) {
    __shared__ unsigned int Wf[4096];   // 16 KB (gemm role)
    __shared__ int hist[4][CBKT];       // per-wave hist (binA role)
    __shared__ int wof[4][CBKT];
    __shared__ int base[CBKT];

    if (blockIdx.x >= GEMM_BLOCKS) {
        const int tid = threadIdx.x;
        const int wv = tid >> 6;
        for (int tile = blockIdx.x - GEMM_BLOCKS; tile < NTILE_A; tile += BINA_BLOCKS) {
            const int e0 = tile * TILE_A;
            int d[4], s[4], bk[4], rk[4];
            bool val[4];
#pragma unroll
            for (int j = 0; j < 4; ++j) {
                int e = e0 + j * 256 + tid;
                val[j] = e < N_EDGES;
                int ee = val[j] ? e : 0;
                d[j] = __builtin_nontemporal_load(dst + ee);
                s[j] = __builtin_nontemporal_load(src + ee);
                bk[j] = d[j] >> 11;
            }
            hist[tid >> 6][tid & 63] = 0;
            __syncthreads();
#pragma unroll
            for (int j = 0; j < 4; ++j)
                if (val[j]) rk[j] = atomicAdd(&hist[wv][bk[j]], 1);
            __syncthreads();
            if (tid < CBKT) {
                int h0 = hist[0][tid], h1 = hist[1][tid];
                int h2 = hist[2][tid], h3 = hist[3][tid];
                int tot = h0 + h1 + h2 + h3;
                base[tid] = tot ? atomicAdd(&ctail[tid * 16], tot) : 0;
                wof[0][tid] = 0; wof[1][tid] = h0;
                wof[2][tid] = h0 + h1; wof[3][tid] = h0 + h1 + h2;
            }
            __syncthreads();
#pragma unroll
            for (int j = 0; j < 4; ++j) {
                if (val[j]) {
                    int pos = base[bk[j]] + wof[wv][bk[j]] + rk[j];
                    if (pos < CCAP)
                        cbuf[(size_t)bk[j] * CCAP + pos] =
                            ((unsigned int)(d[j] & 2047) << 17) | (unsigned int)s[j];
                }
            }
        }
        return;
    }

    // ---- gemm role ----
    for (int idx = threadIdx.x; idx < 4096; idx += 256) {
        int kk = idx >> 10, n = (idx >> 8) & 3, l = (idx >> 2) & 63, r = idx & 3;
        int k = kk * 32 + ((l >> 4) << 3) + 2 * r;
        int c = n * 16 + (l & 15);
        unsigned int lov = f32_to_bf16(W[k * CLASSES + c]);
        unsigned int hiv = f32_to_bf16(W[(k + 1) * CLASSES + c]);
        Wf[idx] = lov | (hiv << 16);
    }
    __syncthreads();

    const int wave = threadIdx.x >> 6;
    const int lane = threadIdx.x & 63;
    const int row_in = lane & 15;
    const int kb = (lane >> 4) << 3;

    const int widx = blockIdx.x * 4 + wave;
    if (widx >= NSTRIP / 2) return;

    const float* xr0 = x + (size_t)(widx * 32 + row_in) * D_FEAT + kb;
    const float* xr1 = xr0 + 16 * D_FEAT;

    fvec4 v[16];
#pragma unroll
    for (int kk = 0; kk < 4; ++kk) {
        v[kk * 2 + 0] = __builtin_nontemporal_load((const fvec4*)(xr0 + kk * 32));
        v[kk * 2 + 1] = __builtin_nontemporal_load((const fvec4*)(xr0 + kk * 32 + 4));
        v[8 + kk * 2 + 0] = __builtin_nontemporal_load((const fvec4*)(xr1 + kk * 32));
        v[8 + kk * 2 + 1] = __builtin_nontemporal_load((const fvec4*)(xr1 + kk * 32 + 4));
    }

    bf16x8 af0[4], af1[4];
#pragma unroll
    for (int kk = 0; kk < 4; ++kk) {
        fvec4 a = v[kk * 2], c = v[kk * 2 + 1];
        bf16x8 t0;
        t0[0] = (short)f32_to_bf16(a.x); t0[1] = (short)f32_to_bf16(a.y);
        t0[2] = (short)f32_to_bf16(a.z); t0[3] = (short)f32_to_bf16(a.w);
        t0[4] = (short)f32_to_bf16(c.x); t0[5] = (short)f32_to_bf16(c.y);
        t0[6] = (short)f32_to_bf16(c.z); t0[7] = (short)f32_to_bf16(c.w);
        af0[kk] = t0;
        fvec4 d = v[8 + kk * 2], e = v[8 + kk * 2 + 1];
        bf16x8 t1;
        t1[0] = (short)f32_to_bf16(d.x); t1[1] = (short)f32_to_bf16(d.y);
        t1[2] = (short)f32_to_bf16(d.z); t1[3] = (short)f32_to_bf16(d.w);
        t1[4] = (short)f32_to_bf16(e.x); t1[5] = (short)f32_to_bf16(e.y);
        t1[6] = (short)f32_to_bf16(e.z); t1[7] = (short)f32_to_bf16(e.w);
        af1[kk] = t1;
    }

    f32x4 acc0[4] = {{0.f,0.f,0.f,0.f},{0.f,0.f,0.f,0.f},{0.f,0.f,0.f,0.f},{0.f,0.f,0.f,0.f}};
    f32x4 acc1[4] = {{0.f,0.f,0.f,0.f},{0.f,0.f,0.f,0.f},{0.f,0.f,0.f,0.f},{0.f,0.f,0.f,0.f}};
#pragma unroll
    for (int n = 0; n < 4; ++n) {
#pragma unroll
        for (int kk = 0; kk < 4; ++kk) {
            bf16x8 bfr = *(const bf16x8*)&Wf[((kk * 4 + n) * 64 + lane) * 4];
            acc0[n] = __builtin_amdgcn_mfma_f32_16x16x32_bf16(af0[kk], bfr, acc0[n], 0, 0, 0);
            acc1[n] = __builtin_amdgcn_mfma_f32_16x16x32_bf16(af1[kk], bfr, acc1[n], 0, 0, 0);
        }
    }

    unsigned short* yr0 = ybu + (size_t)(widx * 2) * 16 * CLASSES;
    unsigned short* yr1 = yr0 + 16 * CLASSES;
#pragma unroll
    for (int n = 0; n < 4; ++n) {
        int c = n * 16 + (lane & 15);
        int pos = ((c & 31) << 1) + (c >> 5);
#pragma unroll
        for (int r = 0; r < 4; ++r) {
            yr0[((lane >> 4) * 4 + r) * CLASSES + pos] = f32_to_bf16(acc0[n][r]);
            yr1[((lane >> 4) * 4 + r) * CLASSES + pos] = f32_to_bf16(acc1[n][r]);
        }
    }
}

// Kernel 3: one block per 64-node partition (p = dst>>6; bucket bk = p>>5,
// fine bin = p&31). The partition's entries are found by SCANNING its coarse
// bucket (65 KB, L2-resident, shared by the 32 sibling blocks) and ballot-
// compacting matches into LDS — this replaces the whole binB kernel.
// Then CSR-sort + register gather (8 nodes per half-wave, branch-free
// DUMMY padding), epilogue adds self + bias.
__global__ __launch_bounds__(256) void accum_kernel(
        const unsigned int* __restrict__ yb, const int* __restrict__ ctail,
        const unsigned int* __restrict__ cbuf, const float* __restrict__ b,
        float* __restrict__ out) {
    __shared__ unsigned int ent[PCAP];
    __shared__ int sorted_s[PCAP];
    __shared__ int cnt_s[NPP], start_s[NPP], cursor_s[NPP];
    __shared__ int tot_s;

    const int tid = threadIdx.x;
    const int lane = tid & 63;
    const int p = blockIdx.x;
    const int bk = p >> 5;
    const int bin = p & 31;

    if (tid < NPP) cnt_s[tid] = 0;
    if (tid == 0) tot_s = 0;
    __syncthreads();

    // scan + ballot-compact: lane 0 of each wave has the smallest index, so
    // whenever any lane is active, lane 0 is active (safe shfl source).
    const int cnt = min(ctail[bk * 16], CCAP);
    const unsigned int* cb = cbuf + (size_t)bk * CCAP;
    for (int i = tid; i < cnt; i += 256) {
        unsigned int e = cb[i];
        bool match = ((int)(e >> 23) == bin);
        unsigned long long m = __ballot(match);
        int base = 0;
        if (lane == 0 && m) base = atomicAdd(&tot_s, (int)__popcll(m));
        base = __shfl(base, 0);
        if (match) {
            int pos = base + (int)__popcll(m & ((1ull << lane) - 1ull));
            if (pos < PCAP) ent[pos] = e;
        }
    }
    __syncthreads();

    const int tot = min(tot_s, PCAP);
    for (int i = tid; i < tot; i += 256) atomicAdd(&cnt_s[(ent[i] >> 17) & 63], 1);
    __syncthreads();

    if (tid < 64) {  // wave 0: prefix scan over 64 node counts
        int v = cnt_s[tid];
        int incl = v;
#pragma unroll
        for (int o = 1; o < 64; o <<= 1) {
            int u = __shfl_up(incl, o, 64);
            if (tid >= o) incl += u;
        }
        start_s[tid] = incl - v;
        cursor_s[tid] = incl - v;
    }
    __syncthreads();

    for (int i = tid; i < tot; i += 256) {
        unsigned int e = ent[i];
        int pos = atomicAdd(&cursor_s[(e >> 17) & 63], 1);
        sorted_s[pos] = (int)(e & 0x1FFFFu);
    }
    __syncthreads();

    const int hw = tid >> 5;   // half-wave 0..7, owns local nodes hw*8..hw*8+7
    const int t = tid & 31;
    const float b0 = b[t], b1 = b[t + 32];

    const int r0 = hw * 8;
    int deg[8], st[8];
#pragma unroll
    for (int k = 0; k < 8; ++k) { deg[k] = cnt_s[r0 + k]; st[k] = start_s[r0 + k]; }
    int dmax = 0;
#pragma unroll
    for (int k = 0; k < 8; ++k) dmax = max(dmax, deg[k]);

    float2 a[8];
#pragma unroll
    for (int k = 0; k < 8; ++k) a[k] = make_float2(0.f, 0.f);

    for (int cb2 = 0; cb2 < dmax; cb2 += 32) {
        int idx[8];
#pragma unroll
        for (int k = 0; k < 8; ++k)
            idx[k] = (cb2 + t < deg[k]) ? sorted_s[st[k] + cb2 + t] : DUMMY;
        int lim = min(32, dmax - cb2);
#pragma unroll 2
        for (int j = 0; j < lim; ++j) {
#pragma unroll
            for (int k = 0; k < 8; ++k) {
                int sk = __shfl(idx[k], j, 32);
                unsigned int yk = yb[(size_t)sk * 32 + t];
                a[k].x += bf16_lo(yk);
                a[k].y += bf16_hi(yk);
            }
        }
    }

#pragma unroll
    for (int k = 0; k < 8; ++k) {
        int node = p * NPP + r0 + k;
        if (node < N_NODES) {
            unsigned int u = yb[(size_t)node * 32 + t];
            out[(size_t)node * 64 + t] = a[k].x + bf16_lo(u) + b0;
            out[(size_t)node * 64 + t + 32] = a[k].y + bf16_hi(u) + b1;
        }
    }
}

extern "C" void kernel_launch(void* const* d_in, const int* in_sizes, int n_in,
                              void* d_out, int out_size, void* d_ws, size_t ws_size,
                              hipStream_t stream) {
    const float* x = (const float*)d_in[0];
    const int* edge = (const int*)d_in[1];  // [2, N_EDGES] int32
    const float* W = (const float*)d_in[2];
    const float* b = (const float*)d_in[3];
    float* out = (float*)d_out;

    // workspace layout (~17.5 MB):
    int* ctail = (int*)d_ws;                               // 64*16 ints (line-padded)
    unsigned int* cbuf = (unsigned int*)d_ws + 1024;       // 64*18432 dw = 4.7 MB
    unsigned int* yb = cbuf + (size_t)CBKT * CCAP;         // 100001*32 dw = 12.8 MB
    unsigned short* ybu = (unsigned short*)yb;

    const int* src = edge;
    const int* dst = edge + N_EDGES;

    zq_kernel<<<5, 256, 0, stream>>>(ctail, yb);
    fused_gemm_binA_kernel<<<GEMM_BLOCKS + BINA_BLOCKS, 256, 0, stream>>>(
        x, W, src, dst, ctail, cbuf, ybu);
    accum_kernel<<<NPART, 256, 0, stream>>>(yb, ctail, cbuf, b, out);
}

// Round 17
// 73.374 us; speedup vs baseline: 1.5575x; 1.5575x over previous
//
#include <hip/hip_runtime.h>

#define N_NODES 100000
#define D_FEAT 128
#define CLASSES 64
#define N_EDGES 800000
#define DUMMY N_NODES        // zero row in Y table
#define NPP 32               // nodes per partition
#define NPART 3125           // N_NODES / NPP exactly
#define PCAP 448             // per-partition cap: mean 256, +12 sigma
#define CBKT 64              // coarse buckets (dst>>11), 49 used
#define CCAP 18432           // per-bucket cap: mean 16.3k, +16 sigma
#define NSTRIP (N_NODES / 16)  // 6250
#define GEMM_BLOCKS 782
#define BINA_BLOCKS 782
#define TILE_A 1024
#define NTILE_A 782          // ceil(N_EDGES / TILE_A)
#define BPB 16               // binB blocks per bucket

typedef short bf16x8 __attribute__((ext_vector_type(8)));
typedef float f32x4 __attribute__((ext_vector_type(4)));
typedef float fvec4 __attribute__((ext_vector_type(4)));

static __device__ __forceinline__ unsigned short f32_to_bf16(float f) {
    unsigned int u = __float_as_uint(f);
    u += 0x7FFFu + ((u >> 16) & 1u);  // round-to-nearest-even
    return (unsigned short)(u >> 16);
}
static __device__ __forceinline__ float bf16_lo(unsigned int u) {
    return __uint_as_float(u << 16);
}
static __device__ __forceinline__ float bf16_hi(unsigned int u) {
    return __uint_as_float(u & 0xFFFF0000u);
}

// Kernel 1: zero coarse+fine tails and the dummy Y row.
__global__ void zq_kernel(int* __restrict__ tails, unsigned int* __restrict__ yb) {
    int i = blockIdx.x * blockDim.x + threadIdx.x;
    if (i < 1024 + NPART * 16 + 176) tails[i] = 0;
    if (i < 32) yb[(size_t)DUMMY * 32 + i] = 0;
}

// Kernel 2 (fused): blocks [0,GEMM_BLOCKS) = MFMA GEMM Y=X@W (2 strips/wave,
// batched nontemporal loads). Blocks [GEMM_BLOCKS,+BINA_BLOCKS) = coarse
// multisplit (1024-edge tiles, 4 edges/thread, per-wave private histograms,
// 3 barriers/tile). Proven structure from R15 (80.7us total).
__global__ __launch_bounds__(256) void fused_gemm_binA_kernel(
        const float* __restrict__ x, const float* __restrict__ W,
        const int* __restrict__ src, const int* __restrict__ dst,
        int* __restrict__ ctail, unsigned int* __restrict__ cbuf,
        unsigned short* __restrict__ ybu) {
    __shared__ unsigned int Wf[4096];   // 16 KB (gemm role)
    __shared__ int hist[4][CBKT];       // per-wave hist (binA role)
    __shared__ int wof[4][CBKT];
    __shared__ int base[CBKT];

    if (blockIdx.x >= GEMM_BLOCKS) {
        const int tid = threadIdx.x;
        const int wv = tid >> 6;
        for (int tile = blockIdx.x - GEMM_BLOCKS; tile < NTILE_A; tile += BINA_BLOCKS) {
            const int e0 = tile * TILE_A;
            int d[4], s[4], bk[4], rk[4];
            bool val[4];
#pragma unroll
            for (int j = 0; j < 4; ++j) {
                int e = e0 + j * 256 + tid;
                val[j] = e < N_EDGES;
                int ee = val[j] ? e : 0;
                d[j] = __builtin_nontemporal_load(dst + ee);
                s[j] = __builtin_nontemporal_load(src + ee);
                bk[j] = d[j] >> 11;
            }
            hist[tid >> 6][tid & 63] = 0;
            __syncthreads();
#pragma unroll
            for (int j = 0; j < 4; ++j)
                if (val[j]) rk[j] = atomicAdd(&hist[wv][bk[j]], 1);
            __syncthreads();
            if (tid < CBKT) {
                int h0 = hist[0][tid], h1 = hist[1][tid];
                int h2 = hist[2][tid], h3 = hist[3][tid];
                int tot = h0 + h1 + h2 + h3;
                base[tid] = tot ? atomicAdd(&ctail[tid * 16], tot) : 0;
                wof[0][tid] = 0; wof[1][tid] = h0;
                wof[2][tid] = h0 + h1; wof[3][tid] = h0 + h1 + h2;
            }
            __syncthreads();
#pragma unroll
            for (int j = 0; j < 4; ++j) {
                if (val[j]) {
                    int pos = base[bk[j]] + wof[wv][bk[j]] + rk[j];
                    if (pos < CCAP)
                        cbuf[(size_t)bk[j] * CCAP + pos] =
                            ((unsigned int)(d[j] & 2047) << 17) | (unsigned int)s[j];
                }
            }
        }
        return;
    }

    // ---- gemm role ----
    for (int idx = threadIdx.x; idx < 4096; idx += 256) {
        int kk = idx >> 10, n = (idx >> 8) & 3, l = (idx >> 2) & 63, r = idx & 3;
        int k = kk * 32 + ((l >> 4) << 3) + 2 * r;
        int c = n * 16 + (l & 15);
        unsigned int lov = f32_to_bf16(W[k * CLASSES + c]);
        unsigned int hiv = f32_to_bf16(W[(k + 1) * CLASSES + c]);
        Wf[idx] = lov | (hiv << 16);
    }
    __syncthreads();

    const int wave = threadIdx.x >> 6;
    const int lane = threadIdx.x & 63;
    const int row_in = lane & 15;
    const int kb = (lane >> 4) << 3;

    const int widx = blockIdx.x * 4 + wave;
    if (widx >= NSTRIP / 2) return;

    const float* xr0 = x + (size_t)(widx * 32 + row_in) * D_FEAT + kb;
    const float* xr1 = xr0 + 16 * D_FEAT;

    fvec4 v[16];
#pragma unroll
    for (int kk = 0; kk < 4; ++kk) {
        v[kk * 2 + 0] = __builtin_nontemporal_load((const fvec4*)(xr0 + kk * 32));
        v[kk * 2 + 1] = __builtin_nontemporal_load((const fvec4*)(xr0 + kk * 32 + 4));
        v[8 + kk * 2 + 0] = __builtin_nontemporal_load((const fvec4*)(xr1 + kk * 32));
        v[8 + kk * 2 + 1] = __builtin_nontemporal_load((const fvec4*)(xr1 + kk * 32 + 4));
    }

    bf16x8 af0[4], af1[4];
#pragma unroll
    for (int kk = 0; kk < 4; ++kk) {
        fvec4 a = v[kk * 2], c = v[kk * 2 + 1];
        bf16x8 t0;
        t0[0] = (short)f32_to_bf16(a.x); t0[1] = (short)f32_to_bf16(a.y);
        t0[2] = (short)f32_to_bf16(a.z); t0[3] = (short)f32_to_bf16(a.w);
        t0[4] = (short)f32_to_bf16(c.x); t0[5] = (short)f32_to_bf16(c.y);
        t0[6] = (short)f32_to_bf16(c.z); t0[7] = (short)f32_to_bf16(c.w);
        af0[kk] = t0;
        fvec4 d = v[8 + kk * 2], e = v[8 + kk * 2 + 1];
        bf16x8 t1;
        t1[0] = (short)f32_to_bf16(d.x); t1[1] = (short)f32_to_bf16(d.y);
        t1[2] = (short)f32_to_bf16(d.z); t1[3] = (short)f32_to_bf16(d.w);
        t1[4] = (short)f32_to_bf16(e.x); t1[5] = (short)f32_to_bf16(e.y);
        t1[6] = (short)f32_to_bf16(e.z); t1[7] = (short)f32_to_bf16(e.w);
        af1[kk] = t1;
    }

    f32x4 acc0[4] = {{0.f,0.f,0.f,0.f},{0.f,0.f,0.f,0.f},{0.f,0.f,0.f,0.f},{0.f,0.f,0.f,0.f}};
    f32x4 acc1[4] = {{0.f,0.f,0.f,0.f},{0.f,0.f,0.f,0.f},{0.f,0.f,0.f,0.f},{0.f,0.f,0.f,0.f}};
#pragma unroll
    for (int n = 0; n < 4; ++n) {
#pragma unroll
        for (int kk = 0; kk < 4; ++kk) {
            bf16x8 bfr = *(const bf16x8*)&Wf[((kk * 4 + n) * 64 + lane) * 4];
            acc0[n] = __builtin_amdgcn_mfma_f32_16x16x32_bf16(af0[kk], bfr, acc0[n], 0, 0, 0);
            acc1[n] = __builtin_amdgcn_mfma_f32_16x16x32_bf16(af1[kk], bfr, acc1[n], 0, 0, 0);
        }
    }

    unsigned short* yr0 = ybu + (size_t)(widx * 2) * 16 * CLASSES;
    unsigned short* yr1 = yr0 + 16 * CLASSES;
#pragma unroll
    for (int n = 0; n < 4; ++n) {
        int c = n * 16 + (lane & 15);
        int pos = ((c & 31) << 1) + (c >> 5);
#pragma unroll
        for (int r = 0; r < 4; ++r) {
            yr0[((lane >> 4) * 4 + r) * CLASSES + pos] = f32_to_bf16(acc0[n][r]);
            yr1[((lane >> 4) * 4 + r) * CLASSES + pos] = f32_to_bf16(acc1[n][r]);
        }
    }
}

// Kernel 3: fine multisplit, 64 bins/bucket (partition = dst>>5). Per-wave
// private histograms, 1024-entry tiles, 16 blocks per bucket.
__global__ __launch_bounds__(256) void binB_kernel(
        const int* __restrict__ ctail, const unsigned int* __restrict__ cbuf,
        int* __restrict__ ftail, unsigned int* __restrict__ fbuf) {
    __shared__ int hist[4][64];
    __shared__ int wof[4][64];
    __shared__ int base[64];
    const int tid = threadIdx.x;
    const int wv = tid >> 6;
    const int bk = blockIdx.x / BPB;
    const int sub = blockIdx.x % BPB;
    const int cnt = min(ctail[bk * 16], CCAP);
    const unsigned int* cb = cbuf + (size_t)bk * CCAP;

    for (int t0 = sub * 1024; t0 < cnt; t0 += BPB * 1024) {
        unsigned int ent[4];
        int bin[4], rk[4];
        bool val[4];
#pragma unroll
        for (int j = 0; j < 4; ++j) {
            int i = t0 + j * 256 + tid;
            val[j] = i < cnt;
            ent[j] = val[j] ? cb[i] : 0u;
            bin[j] = (int)(ent[j] >> 22) & 63;  // d11>>5
        }
        hist[tid >> 6][tid & 63] = 0;
        __syncthreads();
#pragma unroll
        for (int j = 0; j < 4; ++j)
            if (val[j]) rk[j] = atomicAdd(&hist[wv][bin[j]], 1);
        __syncthreads();
        if (tid < 64) {
            int h0 = hist[0][tid], h1 = hist[1][tid];
            int h2 = hist[2][tid], h3 = hist[3][tid];
            int tot = h0 + h1 + h2 + h3;
            int qid = (bk << 6) | tid;
            base[tid] = tot ? atomicAdd(&ftail[qid * 16], tot) : 0;
            wof[0][tid] = 0; wof[1][tid] = h0;
            wof[2][tid] = h0 + h1; wof[3][tid] = h0 + h1 + h2;
        }
        __syncthreads();
#pragma unroll
        for (int j = 0; j < 4; ++j) {
            if (val[j]) {
                int pos = base[bin[j]] + wof[wv][bin[j]] + rk[j];
                if (pos < PCAP) {
                    int qid = (bk << 6) | bin[j];
                    int d11 = (int)(ent[j] >> 17);
                    fbuf[(size_t)qid * PCAP + pos] =
                        ((unsigned int)(d11 & 31) << 17) | (ent[j] & 0x1FFFFu);
                }
            }
        }
        __syncthreads();
    }
}

// Kernel 4: one block per 32-node partition (3125 blocks — 2x R15's
// parallelism; 4 nodes per half-wave cuts DUMMY-padding waste 1.9x->1.6x).
// Stage fine queue into LDS, CSR-sort, register gather, epilogue.
__global__ __launch_bounds__(256) void accum_kernel(
        const unsigned int* __restrict__ yb, const int* __restrict__ ftail,
        const unsigned int* __restrict__ fbuf, const float* __restrict__ b,
        float* __restrict__ out) {
    __shared__ unsigned int ent[PCAP];
    __shared__ int sorted_s[PCAP];
    __shared__ int cnt_s[NPP], start_s[NPP], cursor_s[NPP];

    const int tid = threadIdx.x;
    const int p = blockIdx.x;

    if (tid < NPP) cnt_s[tid] = 0;
    __syncthreads();

    const int tot = min(ftail[p * 16], PCAP);
    const unsigned int* fq = fbuf + (size_t)p * PCAP;
    for (int i = tid; i < tot; i += 256) ent[i] = fq[i];
    __syncthreads();

    for (int i = tid; i < tot; i += 256) atomicAdd(&cnt_s[(ent[i] >> 17) & 31], 1);
    __syncthreads();

    if (tid < NPP) {  // prefix scan over 32 node counts
        int v = cnt_s[tid];
        int incl = v;
#pragma unroll
        for (int o = 1; o < NPP; o <<= 1) {
            int u = __shfl_up(incl, o, NPP);
            if ((tid & (NPP - 1)) >= o) incl += u;
        }
        start_s[tid] = incl - v;
        cursor_s[tid] = incl - v;
    }
    __syncthreads();

    for (int i = tid; i < tot; i += 256) {
        unsigned int e = ent[i];
        int pos = atomicAdd(&cursor_s[(e >> 17) & 31], 1);
        sorted_s[pos] = (int)(e & 0x1FFFFu);
    }
    __syncthreads();

    const int hw = tid >> 5;   // half-wave 0..7, owns local nodes hw*4..hw*4+3
    const int t = tid & 31;
    const float b0 = b[t], b1 = b[t + 32];

    const int r0 = hw * 4;
    int deg[4], st[4];
#pragma unroll
    for (int k = 0; k < 4; ++k) { deg[k] = cnt_s[r0 + k]; st[k] = start_s[r0 + k]; }
    int dmax = 0;
#pragma unroll
    for (int k = 0; k < 4; ++k) dmax = max(dmax, deg[k]);

    float2 a[4];
#pragma unroll
    for (int k = 0; k < 4; ++k) a[k] = make_float2(0.f, 0.f);

    for (int cb2 = 0; cb2 < dmax; cb2 += 32) {
        int idx[4];
#pragma unroll
        for (int k = 0; k < 4; ++k)
            idx[k] = (cb2 + t < deg[k]) ? sorted_s[st[k] + cb2 + t] : DUMMY;
        int lim = min(32, dmax - cb2);
#pragma unroll 4
        for (int j = 0; j < lim; ++j) {
#pragma unroll
            for (int k = 0; k < 4; ++k) {
                int sk = __shfl(idx[k], j, 32);
                unsigned int yk = yb[(size_t)sk * 32 + t];
                a[k].x += bf16_lo(yk);
                a[k].y += bf16_hi(yk);
            }
        }
    }

#pragma unroll
    for (int k = 0; k < 4; ++k) {
        int node = p * NPP + r0 + k;
        unsigned int u = yb[(size_t)node * 32 + t];
        out[(size_t)node * 64 + t] = a[k].x + bf16_lo(u) + b0;
        out[(size_t)node * 64 + t + 32] = a[k].y + bf16_hi(u) + b1;
    }
}

extern "C" void kernel_launch(void* const* d_in, const int* in_sizes, int n_in,
                              void* d_out, int out_size, void* d_ws, size_t ws_size,
                              hipStream_t stream) {
    const float* x = (const float*)d_in[0];
    const int* edge = (const int*)d_in[1];  // [2, N_EDGES] int32
    const float* W = (const float*)d_in[2];
    const float* b = (const float*)d_in[3];
    float* out = (float*)d_out;

    // workspace layout (~23.5 MB):
    int* ctail = (int*)d_ws;                               // 1024 ints
    int* ftail = ctail + 1024;                             // 3125*16 -> pad 50176
    unsigned int* cbuf = (unsigned int*)(ftail + 50176);   // 64*18432 dw = 4.7 MB
    unsigned int* fbuf = cbuf + (size_t)CBKT * CCAP;       // 3125*448 dw = 5.6 MB
    unsigned int* yb = fbuf + (size_t)NPART * PCAP;        // 100001*32 dw = 12.8 MB
    unsigned short* ybu = (unsigned short*)yb;

    const int* src = edge;
    const int* dst = edge + N_EDGES;

    zq_kernel<<<(1024 + NPART * 16 + 176 + 255) / 256, 256, 0, stream>>>(ctail, yb);
    fused_gemm_binA_kernel<<<GEMM_BLOCKS + BINA_BLOCKS, 256, 0, stream>>>(
        x, W, src, dst, ctail, cbuf, ybu);
    binB_kernel<<<49 * BPB, 256, 0, stream>>>(ctail, cbuf, ftail, fbuf);
    accum_kernel<<<NPART, 256, 0, stream>>>(yb, ftail, fbuf, b, out);
}